// Round 8
// baseline (47.508 us; speedup 1.0000x reference)
//
#include <hip/hip_runtime.h>
#include <math.h>

#define BS 16
#define NQ 100
#define NPTS 25
#define VOC 96
#define NC 97              // VOC+1 classes incl. padding
#define MAXLEN 25
#define NGT 32
#define EDIM 300
#define NCOL 512           // BS*NGT
#define NDIM 50            // NPTS*2
#define RPB 10             // rows per assemble block (divides 100)

// ---------------- workspace layout (floats) ----------------
#define WS_GRAM 0                       // 97*96 = 9312 (row 96 = zeros)
#define WS_LOGP (WS_GRAM + NC * VOC)    // 1600*96
#define WS_CC   (WS_LOGP + 1600 * VOC)  // 1600
#define WS_TGTT (WS_CC + 1600)          // 50*512

#define GRAM_BLKS VOC              // 96
#define PRED_BLKS 1600
#define TR_BLKS 200                // 200*128 = 25600
#define K1_BLKS (GRAM_BLKS + PRED_BLKS + TR_BLKS)

// ---- K1: role-split: gram rows | pred (logp + focal) | tgt-point transpose
__global__ __launch_bounds__(128) void k1_kernel(
        const float* __restrict__ logits1,   // (1600,25,1)
        const float* __restrict__ tlogits,   // (1600,25,97)
        const float* __restrict__ cen,       // (96,300)
        const float* __restrict__ tgt_pts,   // (512,50)
        float* __restrict__ gram, float* __restrict__ logp,
        float* __restrict__ cost_class, float* __restrict__ tgtT) {
    __shared__ float smem[448];              // gram: row[0..300)+red[320..448); pred: pA[2][97]
    int blk = blockIdx.x, tid = threadIdx.x;
    int wave = tid >> 6, lane = tid & 63;

    if (blk < GRAM_BLKS) {
        // ---- gram row v = blk: softmax_c( dot(cen[v],cen[c]) / sqrt(300) ), no max pass
        float* row = smem;                   // 300
        float* red = smem + 320;             // 128
        for (int k = tid; k < EDIM; k += 128) row[k] = cen[blk * EDIM + k];
        if (blk == 0 && tid < VOC) gram[VOC * VOC + tid] = 0.f;   // zero pad row
        __syncthreads();
        float e = 0.f;
        if (tid < VOC) {
            float a0 = 0.f, a1 = 0.f;
            const float* c = cen + (size_t)tid * EDIM;
            for (int k = 0; k < EDIM; k += 2) { a0 += row[k] * c[k]; a1 += row[k + 1] * c[k + 1]; }
            e = __expf((a0 + a1) * 0.05773502691896258f);
        }
        red[tid] = e;
        __syncthreads();
        for (int s = 64; s; s >>= 1) { if (tid < s) red[tid] += red[tid + s]; __syncthreads(); }
        if (tid < VOC) gram[blk * VOC + tid] = e / red[0];
    } else if (blk < GRAM_BLKS + PRED_BLKS) {
        // ---- pred unit: register-resident softmax, interleaved cross-lane reductions
        int u = blk - GRAM_BLKS;
        const float* base = tlogits + (size_t)u * NPTS * NC;
        float e0[13], e1[13], s[13], vm[13];
        int p0 = wave * 13;                  // wave0: 13 pts, wave1: 12 pts
#pragma unroll
        for (int i = 0; i < 13; ++i) {
            int p = p0 + i;
            bool ok = p < NPTS;
            vm[i] = ok ? 1.f : 0.f;
            int pe = ok ? p : 0;
            float x0 = base[pe * NC + lane];
            float x1 = (lane < 33) ? base[pe * NC + 64 + lane] : 0.f;
            e0[i] = __expf(x0);
            e1[i] = (lane < 33) ? __expf(x1) : 0.f;
            s[i] = e0[i] + e1[i];
        }
        // 13 independent 6-step xor-reduce chains, interleaved -> pipelined
#pragma unroll
        for (int st = 32; st; st >>= 1) {
#pragma unroll
            for (int i = 0; i < 13; ++i) s[i] += __shfl_xor(s[i], st);
        }
        float part0 = 0.f, part1 = 0.f;
#pragma unroll
        for (int i = 0; i < 13; ++i) {
            float rinv = vm[i] / s[i];       // invalid slot -> 0 (s finite >0)
            part0 += e0[i] * rinv;
            part1 += e1[i] * rinv;
        }
        float* pA = smem;                    // [2][97]
        pA[wave * 97 + lane] = part0;
        if (lane < 33) pA[wave * 97 + 64 + lane] = part1;
        __syncthreads();
        if (tid < VOC) {
            float tot = (pA[tid] + pA[97 + tid]) * 0.04f;
            logp[(size_t)u * VOC + tid] = __logf(fmaxf(tot, 1e-6f));
        }
        if (wave == 1) {                     // wave1 has the spare slot
            float sig = 0.f;
            if (lane < NPTS) { float x = logits1[u * NPTS + lane]; sig = 1.f / (1.f + __expf(-x)); }
#pragma unroll
            for (int o = 32; o; o >>= 1) sig += __shfl_xor(sig, o);
            if (lane == 0) {
                float prob = sig * 0.04f;
                float negc = 0.75f * prob * prob * (-__logf(1.f - prob + 1e-8f));
                float posc = 0.25f * (1.f - prob) * (1.f - prob) * (-__logf(prob + 1e-8f));
                cost_class[u] = posc - negc;
            }
        }
    } else {
        // ---- transpose tgt points (512,50) -> (50,512)
        int g = (blk - GRAM_BLKS - PRED_BLKS) * 128 + tid;   // < 25600 exactly
        int k = g / NCOL;
        int j = g - k * NCOL;
        tgtT[g] = tgt_pts[(size_t)j * NDIM + k];
    }
}

// ================= K2: fused stats + assemble =================
// 160 blocks x 512 thr; block owns rows r0 = blk*10 .. r0+9, all in image b = blk/10.
__global__ __launch_bounds__(512) void k2_kernel(
        const float* __restrict__ pred_pts,  // (1600,50)
        const float* __restrict__ tgtT,      // (50,512)
        const float* __restrict__ gram,      // (97,96), row 96 zeros
        const int*   __restrict__ texts,     // (512,25)
        const float* __restrict__ logp,      // (1600,96)
        const float* __restrict__ cc,        // (1600,)
        float* __restrict__ out) {           // (1600,512)
    __shared__ float s_stat[NGT][NC];        // ts[0..95], [96]=neg_ent (stride 97)
    __shared__ float s_lp[RPB][VOC];
    __shared__ float s_pp[RPB][NDIM];
    __shared__ float s_cc[RPB];
    __shared__ float s_ct[RPB][NGT];
    __shared__ int   s_tex[NGT * MAXLEN];    // 800

    int blk = blockIdx.x, tid = threadIdx.x;
    int wave = tid >> 6, lane = tid & 63;
    int r0 = blk * RPB;
    int b = blk / (NQ / RPB);                // = r0/100

    for (int i = tid; i < NGT * MAXLEN; i += 512) s_tex[i] = texts[b * NGT * MAXLEN + i];
    for (int i = tid; i < RPB * VOC; i += 512) s_lp[i / VOC][i % VOC] = logp[(size_t)r0 * VOC + i];
    if (tid < RPB * NDIM) s_pp[tid / NDIM][tid % NDIM] = pred_pts[(size_t)r0 * NDIM + tid];
    if (tid < RPB) s_cc[tid] = cc[r0 + tid];
    __syncthreads();

    // ---- stats: 8 waves x 4 g's, fully interleaved chains
    {
        int g0 = wave * 4;
        float a0[4] = {0.f, 0.f, 0.f, 0.f}, a1[4] = {0.f, 0.f, 0.f, 0.f};
        int len[4] = {0, 0, 0, 0};
#pragma unroll
        for (int l = 0; l < MAXLEN; ++l) {
#pragma unroll
            for (int j = 0; j < 4; ++j) {
                int v = s_tex[(g0 + j) * MAXLEN + l];   // wave-uniform LDS broadcast
                len[j] += (v != VOC);
                const float* gr = gram + v * VOC;        // row 96 = zeros
                a0[j] += gr[lane];
                a1[j] += (lane < 32) ? gr[64 + lane] : 0.f;
            }
        }
        float t0[4], t1[4], sv[4];
#pragma unroll
        for (int j = 0; j < 4; ++j) {
            float dinv = 1.f / (float)(len[j] > 0 ? len[j] : 1);
            t0[j] = fmaxf(a0[j] * dinv, 1e-6f);
            t1[j] = (lane < 32) ? fmaxf(a1[j] * dinv, 1e-6f) : 0.f;
            sv[j] = t0[j] + t1[j];
        }
#pragma unroll
        for (int st = 32; st; st >>= 1) {
#pragma unroll
            for (int j = 0; j < 4; ++j) sv[j] += __shfl_xor(sv[j], st);
        }
        float en[4];
#pragma unroll
        for (int j = 0; j < 4; ++j) {
            float inv = 1.f / sv[j];
            t0[j] *= inv; t1[j] *= inv;                  // now normalized ts
            en[j] = t0[j] * __logf(t0[j]) + ((lane < 32) ? t1[j] * __logf(t1[j]) : 0.f);
        }
#pragma unroll
        for (int st = 32; st; st >>= 1) {
#pragma unroll
            for (int j = 0; j < 4; ++j) en[j] += __shfl_xor(en[j], st);
        }
#pragma unroll
        for (int j = 0; j < 4; ++j) {
            int g = g0 + j;
            s_stat[g][lane] = len[j] ? t0[j] : 0.f;
            if (lane < 32) s_stat[g][64 + lane] = len[j] ? t1[j] : 0.f;
            if (lane == 0) s_stat[g][VOC] = len[j] ? en[j] : 100.f;
        }
    }
    __syncthreads();

    // ---- KL: 320 threads, one (row,g) dot each
    if (tid < RPB * NGT) {
        int row = tid >> 5, g = tid & 31;
        const float* L = s_lp[row];              // broadcast
        const float* S = s_stat[g];              // stride 97 -> conflict-free
        float d0 = 0.f, d1 = 0.f, d2 = 0.f, d3 = 0.f;
#pragma unroll
        for (int c = 0; c < VOC; c += 4) {
            d0 += L[c]     * S[c];
            d1 += L[c + 1] * S[c + 1];
            d2 += L[c + 2] * S[c + 2];
            d3 += L[c + 3] * S[c + 3];
        }
        s_ct[row][g] = fmaxf(S[VOC] - (d0 + d1 + d2 + d3), 0.f);
    }
    __syncthreads();

    // ---- joint L1 sweep: 1 col/thread, all 10 rows per tgtT read
    float acc[RPB];
#pragma unroll
    for (int r = 0; r < RPB; ++r) acc[r] = 0.f;
#pragma unroll 5
    for (int k = 0; k < NDIM; ++k) {
        float tv = tgtT[(k << 9) + tid];
#pragma unroll
        for (int r = 0; r < RPB; ++r) acc[r] += fabsf(s_pp[r][k] - tv);
    }

    int gb = tid >> 5, g = tid & 31;
    float text = (gb == b) ? 1.f : 0.f;
#pragma unroll
    for (int r = 0; r < RPB; ++r) {
        out[(size_t)(r0 + r) * NCOL + tid] = s_cc[r] + acc[r] + text * s_ct[r][g];
    }
}

extern "C" void kernel_launch(void* const* d_in, const int* in_sizes, int n_in,
                              void* d_out, int out_size, void* d_ws, size_t ws_size,
                              hipStream_t stream) {
    const float* pred_logits      = (const float*)d_in[0];
    const float* pred_ctrl_points = (const float*)d_in[1];
    const float* pred_text_logits = (const float*)d_in[2];
    const float* tgt_ctrl_points  = (const float*)d_in[3];
    const int*   target_texts     = (const int*)d_in[4];
    const float* centroids        = (const float*)d_in[5];
    float* out = (float*)d_out;
    float* ws  = (float*)d_ws;

    float* gram = ws + WS_GRAM;
    float* logp = ws + WS_LOGP;
    float* cc   = ws + WS_CC;
    float* tgtT = ws + WS_TGTT;

    k1_kernel<<<K1_BLKS, 128, 0, stream>>>(pred_logits, pred_text_logits, centroids,
                                           tgt_ctrl_points, gram, logp, cc, tgtT);
    k2_kernel<<<(BS * NQ) / RPB, 512, 0, stream>>>(pred_ctrl_points, tgtT, gram,
                                                   target_texts, logp, cc, out);
}

// Round 9
// 31.557 us; speedup vs baseline: 1.5055x; 1.5055x over previous
//
#include <hip/hip_runtime.h>
#include <math.h>

#define BS 16
#define NQ 100
#define NPTS 25
#define VOC 96
#define NC 97              // VOC+1 classes incl. padding
#define MAXLEN 25
#define NGT 32
#define EDIM 300
#define NCOL 512           // BS*NGT
#define NDIM 50            // NPTS*2
#define RPB 10             // rows per assemble block (divides 100)

// ---------------- workspace layout (floats) ----------------
#define WS_GRAM 0                       // 97*96 = 9312 (row 96 = zeros)
#define WS_LOGP (WS_GRAM + NC * VOC)    // 1600*96
#define WS_CC   (WS_LOGP + 1600 * VOC)  // 1600
#define WS_TGTT (WS_CC + 1600)          // 50*512

#define GRAM_BLKS VOC              // 96
#define PRED_BLKS 1600
#define TR_BLKS 200                // 200*128 = 25600
#define K1_BLKS (GRAM_BLKS + PRED_BLKS + TR_BLKS)

// ---- K1 (unchanged from R8 — register-resident pred softmax): gram | pred | transpose
__global__ __launch_bounds__(128) void k1_kernel(
        const float* __restrict__ logits1,   // (1600,25,1)
        const float* __restrict__ tlogits,   // (1600,25,97)
        const float* __restrict__ cen,       // (96,300)
        const float* __restrict__ tgt_pts,   // (512,50)
        float* __restrict__ gram, float* __restrict__ logp,
        float* __restrict__ cost_class, float* __restrict__ tgtT) {
    __shared__ float smem[448];              // gram: row[0..300)+red[320..448); pred: pA[2][97]
    int blk = blockIdx.x, tid = threadIdx.x;
    int wave = tid >> 6, lane = tid & 63;

    if (blk < GRAM_BLKS) {
        // ---- gram row v = blk: softmax_c( dot(cen[v],cen[c]) / sqrt(300) ), no max pass
        float* row = smem;                   // 300
        float* red = smem + 320;             // 128
        for (int k = tid; k < EDIM; k += 128) row[k] = cen[blk * EDIM + k];
        if (blk == 0 && tid < VOC) gram[VOC * VOC + tid] = 0.f;   // zero pad row
        __syncthreads();
        float e = 0.f;
        if (tid < VOC) {
            float a0 = 0.f, a1 = 0.f;
            const float* c = cen + (size_t)tid * EDIM;
            for (int k = 0; k < EDIM; k += 2) { a0 += row[k] * c[k]; a1 += row[k + 1] * c[k + 1]; }
            e = __expf((a0 + a1) * 0.05773502691896258f);
        }
        red[tid] = e;
        __syncthreads();
        for (int s = 64; s; s >>= 1) { if (tid < s) red[tid] += red[tid + s]; __syncthreads(); }
        if (tid < VOC) gram[blk * VOC + tid] = e / red[0];
    } else if (blk < GRAM_BLKS + PRED_BLKS) {
        // ---- pred unit: register-resident softmax, interleaved cross-lane reductions
        int u = blk - GRAM_BLKS;
        const float* base = tlogits + (size_t)u * NPTS * NC;
        float e0[13], e1[13], s[13], vm[13];
        int p0 = wave * 13;                  // wave0: 13 pts, wave1: 12 pts
#pragma unroll
        for (int i = 0; i < 13; ++i) {
            int p = p0 + i;
            bool ok = p < NPTS;
            vm[i] = ok ? 1.f : 0.f;
            int pe = ok ? p : 0;
            float x0 = base[pe * NC + lane];
            float x1 = (lane < 33) ? base[pe * NC + 64 + lane] : 0.f;
            e0[i] = __expf(x0);
            e1[i] = (lane < 33) ? __expf(x1) : 0.f;
            s[i] = e0[i] + e1[i];
        }
        // 13 independent 6-step xor-reduce chains, interleaved -> pipelined
#pragma unroll
        for (int st = 32; st; st >>= 1) {
#pragma unroll
            for (int i = 0; i < 13; ++i) s[i] += __shfl_xor(s[i], st);
        }
        float part0 = 0.f, part1 = 0.f;
#pragma unroll
        for (int i = 0; i < 13; ++i) {
            float rinv = vm[i] / s[i];       // invalid slot -> 0 (s finite >0)
            part0 += e0[i] * rinv;
            part1 += e1[i] * rinv;
        }
        float* pA = smem;                    // [2][97]
        pA[wave * 97 + lane] = part0;
        if (lane < 33) pA[wave * 97 + 64 + lane] = part1;
        __syncthreads();
        if (tid < VOC) {
            float tot = (pA[tid] + pA[97 + tid]) * 0.04f;
            logp[(size_t)u * VOC + tid] = __logf(fmaxf(tot, 1e-6f));
        }
        if (wave == 1) {                     // wave1 has the spare slot
            float sig = 0.f;
            if (lane < NPTS) { float x = logits1[u * NPTS + lane]; sig = 1.f / (1.f + __expf(-x)); }
#pragma unroll
            for (int o = 32; o; o >>= 1) sig += __shfl_xor(sig, o);
            if (lane == 0) {
                float prob = sig * 0.04f;
                float negc = 0.75f * prob * prob * (-__logf(1.f - prob + 1e-8f));
                float posc = 0.25f * (1.f - prob) * (1.f - prob) * (-__logf(prob + 1e-8f));
                cost_class[u] = posc - negc;
            }
        }
    } else {
        // ---- transpose tgt points (512,50) -> (50,512)
        int g = (blk - GRAM_BLKS - PRED_BLKS) * 128 + tid;   // < 25600 exactly
        int k = g / NCOL;
        int j = g - k * NCOL;
        tgtT[g] = tgt_pts[(size_t)j * NDIM + k];
    }
}

// ================= K2: fused stats + assemble (R7 base; stats gathers batched) =================
// 160 blocks x 512 thr; block owns rows r0 = blk*10 .. r0+9, all in image b = blk/10.
__global__ __launch_bounds__(512) void k2_kernel(
        const float* __restrict__ pred_pts,  // (1600,50)
        const float* __restrict__ tgtT,      // (50,512)
        const float* __restrict__ gram,      // (97,96), row 96 zeros
        const int*   __restrict__ texts,     // (512,25)
        const float* __restrict__ logp,      // (1600,96)
        const float* __restrict__ cc,        // (1600,)
        float* __restrict__ out) {           // (1600,512)
    __shared__ float s_stat[NGT][NC];        // ts[0..95], [96]=neg_ent (stride 97)
    __shared__ float s_lp[RPB][VOC];
    __shared__ float s_pp[RPB][NDIM];
    __shared__ float s_cc[RPB];
    __shared__ float s_ct[RPB][NGT];
    __shared__ int   s_tex[NGT * MAXLEN];    // 800

    int blk = blockIdx.x, tid = threadIdx.x;
    int wave = tid >> 6, lane = tid & 63;
    int r0 = blk * RPB;
    int b = blk / (NQ / RPB);                // = r0/100

    for (int i = tid; i < NGT * MAXLEN; i += 512) s_tex[i] = texts[b * NGT * MAXLEN + i];
    for (int i = tid; i < RPB * VOC; i += 512) s_lp[i / VOC][i % VOC] = logp[(size_t)r0 * VOC + i];
    if (tid < RPB * NDIM) s_pp[tid / NDIM][tid % NDIM] = pred_pts[(size_t)r0 * NDIM + tid];
    if (tid < RPB) s_cc[tid] = cc[r0 + tid];
    __syncthreads();

    // ---- stats: 8 waves x 4 g's (serial per wave, as R7), gathers batched for ILP
    for (int j = 0; j < NGT / 8; ++j) {
        int g = wave * 4 + j;
        const int* tx = s_tex + g * MAXLEN;
        int vv[MAXLEN];
#pragma unroll
        for (int l = 0; l < MAXLEN; ++l) vv[l] = tx[l];   // 25 independent LDS reads
        int len = 0;
#pragma unroll
        for (int l = 0; l < MAXLEN; ++l) len += (vv[l] != VOC);
        float a0 = 0.f, a1 = 0.f;
#pragma unroll
        for (int l0 = 0; l0 < MAXLEN; l0 += 5) {
            float b0[5], b1[5];
#pragma unroll
            for (int q = 0; q < 5; ++q) {                 // 10 loads issued together
                const float* gr = gram + vv[l0 + q] * VOC;   // row 96 = zeros
                b0[q] = gr[lane];
                b1[q] = (lane < 32) ? gr[64 + lane] : 0.f;
            }
#pragma unroll
            for (int q = 0; q < 5; ++q) { a0 += b0[q]; a1 += b1[q]; }
        }
        float dinv = 1.f / (float)(len > 0 ? len : 1);
        float t0 = fmaxf(a0 * dinv, 1e-6f);
        float t1 = (lane < 32) ? fmaxf(a1 * dinv, 1e-6f) : 0.f;
        float s = t0 + t1;
#pragma unroll
        for (int o = 32; o; o >>= 1) s += __shfl_xor(s, o);
        float inv = 1.f / s;
        float ts0 = t0 * inv, ts1 = t1 * inv;
        float c0 = ts0 * __logf(ts0);
        float c1 = (lane < 32) ? ts1 * __logf(ts1) : 0.f;
        float ent = c0 + c1;
#pragma unroll
        for (int o = 32; o; o >>= 1) ent += __shfl_xor(ent, o);
        s_stat[g][lane] = len ? ts0 : 0.f;
        if (lane < 32) s_stat[g][64 + lane] = len ? ts1 : 0.f;
        if (lane == 0) s_stat[g][VOC] = len ? ent : 100.f;
    }
    __syncthreads();

    // ---- KL: 320 threads, one (row,g) dot each
    if (tid < RPB * NGT) {
        int row = tid >> 5, g = tid & 31;
        const float* L = s_lp[row];              // broadcast
        const float* S = s_stat[g];              // stride 97 -> conflict-free
        float d0 = 0.f, d1 = 0.f, d2 = 0.f, d3 = 0.f;
#pragma unroll
        for (int c = 0; c < VOC; c += 4) {
            d0 += L[c]     * S[c];
            d1 += L[c + 1] * S[c + 1];
            d2 += L[c + 2] * S[c + 2];
            d3 += L[c + 3] * S[c + 3];
        }
        s_ct[row][g] = fmaxf(S[VOC] - (d0 + d1 + d2 + d3), 0.f);
    }
    __syncthreads();

    // ---- joint L1 sweep: 1 col/thread, all 10 rows per tgtT read
    float acc[RPB];
#pragma unroll
    for (int r = 0; r < RPB; ++r) acc[r] = 0.f;
#pragma unroll 5
    for (int k = 0; k < NDIM; ++k) {
        float tv = tgtT[(k << 9) + tid];
#pragma unroll
        for (int r = 0; r < RPB; ++r) acc[r] += fabsf(s_pp[r][k] - tv);
    }

    int gb = tid >> 5, g = tid & 31;
    float text = (gb == b) ? 1.f : 0.f;
#pragma unroll
    for (int r = 0; r < RPB; ++r) {
        out[(size_t)(r0 + r) * NCOL + tid] = s_cc[r] + acc[r] + text * s_ct[r][g];
    }
}

extern "C" void kernel_launch(void* const* d_in, const int* in_sizes, int n_in,
                              void* d_out, int out_size, void* d_ws, size_t ws_size,
                              hipStream_t stream) {
    const float* pred_logits      = (const float*)d_in[0];
    const float* pred_ctrl_points = (const float*)d_in[1];
    const float* pred_text_logits = (const float*)d_in[2];
    const float* tgt_ctrl_points  = (const float*)d_in[3];
    const int*   target_texts     = (const int*)d_in[4];
    const float* centroids        = (const float*)d_in[5];
    float* out = (float*)d_out;
    float* ws  = (float*)d_ws;

    float* gram = ws + WS_GRAM;
    float* logp = ws + WS_LOGP;
    float* cc   = ws + WS_CC;
    float* tgtT = ws + WS_TGTT;

    k1_kernel<<<K1_BLKS, 128, 0, stream>>>(pred_logits, pred_text_logits, centroids,
                                           tgt_ctrl_points, gram, logp, cc, tgtT);
    k2_kernel<<<(BS * NQ) / RPB, 512, 0, stream>>>(pred_ctrl_points, tgtT, gram,
                                                   target_texts, logp, cc, out);
}